// Round 7
// baseline (457.176 us; speedup 1.0000x reference)
//
#include <hip/hip_runtime.h>

// ValueNetwork B=8192, rows=97 (1 self + 96 human), HUMAN_DIM=48.
// One block (256 thr) per batch. GEMMs on MFMA 16x16x32 bf16 hi/lo split.
// R10: X panel row stride 16 -> 24 ushorts (48 B = 12 banks; 16 rows hit 8
// distinct banks x2 = 2-way = free, vs 4-way at stride 16). Kills the 4-way
// conflict on every X ds_read_b128 (step1 A-reads, step2 B-reads) and the
// B4 gather. LDS 30,720 -> ~39.9 KB => 4 blocks/CU; R6/R8/R9 show measured
// occupancy pinned at ~42% for 4 or 5 blocks, so the LDS spend is free.
// Math bit-identical to R9 (2-barrier strip loop, unnorm step4 + post-relu
// invb, exp fused in step2, E single-plane, wave-3 invb).

#define XS 24         // X panel row stride (ushorts); 48B: 16B-aligned, 2-way banks
#define XP (97 * XS)  // ushorts per X column-panel
#define ES 104        // E plane row stride (ushort), 2-way banks
#define WS 56         // W (Xw/AXu) plane row stride (ushort), 2-way banks

typedef short bf16x8 __attribute__((ext_vector_type(8)));
typedef float f32x4 __attribute__((ext_vector_type(4)));

__device__ __forceinline__ unsigned rtne_hi(float f) {
    unsigned u = __float_as_uint(f);
    return (u + 0x7fffu + ((u >> 16) & 1u)) & 0xffff0000u;
}
__device__ __forceinline__ void split2(float f, unsigned short* h, unsigned short* l) {
    unsigned hb = rtne_hi(f);
    float r = f - __uint_as_float(hb);
    *h = (unsigned short)(hb >> 16);
    *l = (unsigned short)(__float_as_uint(r) >> 16);
}
__device__ __forceinline__ unsigned short rtne16(float f) {
    return (unsigned short)(rtne_hi(f) >> 16);
}
__device__ __forceinline__ float bf2f(unsigned short u) {
    return __uint_as_float(((unsigned)u) << 16);
}
__device__ __forceinline__ bf16x8 ldf(const unsigned short* p) {
    return *(const bf16x8*)p;
}

__global__ void vnet_prep(const float* __restrict__ w_a, const float* __restrict__ w1,
                          unsigned short* __restrict__ ws) {
    unsigned short* waT_h = ws;                 // waT[c][k] = w_a[k][c], 48x48
    unsigned short* waT_l = ws + 2304;
    unsigned short* w1T_h = ws + 4608;          // w1T[l][j] = w1[j][l], 64x48
    unsigned short* w1T_l = ws + 4608 + 3072;
    for (int i = threadIdx.x; i < 48 * 48; i += blockDim.x) {
        int c = i / 48, k = i % 48;
        unsigned short h, l; split2(w_a[k * 48 + c], &h, &l);
        waT_h[i] = h; waT_l[i] = l;
    }
    for (int i = threadIdx.x; i < 64 * 48; i += blockDim.x) {
        int lo = i / 48, j = i % 48;
        unsigned short h, l; split2(w1[j * 64 + lo], &h, &l);
        w1T_h[i] = h; w1T_l[i] = l;
    }
}

__global__ __launch_bounds__(256, 4)
void vnet_kernel(const float* __restrict__ state,
                 const float* __restrict__ t_w1, const float* __restrict__ t_b1,
                 const float* __restrict__ t_w2, const float* __restrict__ t_b2,
                 const float* __restrict__ w2,   const float* __restrict__ v_w1,
                 const float* __restrict__ v_b1, const float* __restrict__ v_w2,
                 const float* __restrict__ v_b2, const unsigned short* __restrict__ ws,
                 float* __restrict__ out)
{
    __shared__ __align__(16) unsigned short Xh[3 * XP], Xl[3 * XP];       // 13,968 B each
    __shared__ __align__(16) unsigned short Eh[16 * ES];                  // 3328 B (E single)
    __shared__ __align__(16) unsigned short W0h[16 * WS], W0l[16 * WS];   // 1792 B each
    __shared__ __align__(16) unsigned short W1h[16 * WS], W1l[16 * WS];   // 1792 B each
    __shared__ float a0c[112];     // A row 0 numerators (UNNORMALIZED); [97..111]=0
    __shared__ float e96b[2][16];  // double-buffered exp(S[n][96]) per strip
    __shared__ float psum[2][64];  // double-buffered per-wave row sums [buf][w*16+n]
    __shared__ float invbS[16];    // per-strip 1/rowsum (written by wave 3 in AB)
    __shared__ float pacc[64];     // p accumulator; [0..15] self-state temp at setup
    __shared__ float inv0s;        // 1/rowsum of strip0 row0 (head factor)

    const unsigned short* waT_h = ws;
    const unsigned short* waT_l = ws + 2304;
    const unsigned short* w1T_h = ws + 4608;
    const unsigned short* w1T_l = ws + 4608 + 3072;

    const int tid  = threadIdx.x;
    const int w    = tid >> 6;
    const int lane = tid & 63;
    const int row  = lane & 15;
    const int quad = lane >> 4;
    const int b    = blockIdx.x;
    const float* sb = state + (size_t)b * (96 * 64);
    const bf16x8 ZF = {0, 0, 0, 0, 0, 0, 0, 0};

    // ---------- stage X rows 1..96 into column panels ----------
    if (tid < 16) pacc[tid] = sb[tid];           // self-state temp
    for (int i = tid; i < 96 * 12; i += 256) {
        int r = i / 12, q = i % 12;
        float4 v = *(const float4*)(sb + r * 64 + 16 + 4 * q);
        unsigned short h0, l0, h1v, l1, h2, l2, h3, l3;
        split2(v.x, &h0, &l0); split2(v.y, &h1v, &l1);
        split2(v.z, &h2, &l2); split2(v.w, &h3, &l3);
        int m = 1 + r;
        int o = (q >> 2) * XP + m * XS + (q & 3) * 4;
        *(uint2*)&Xh[o] = make_uint2((unsigned)h0 | ((unsigned)h1v << 16),
                                     (unsigned)h2 | ((unsigned)h3 << 16));
        *(uint2*)&Xl[o] = make_uint2((unsigned)l0 | ((unsigned)l1 << 16),
                                     (unsigned)l2 | ((unsigned)l3 << 16));
    }
    __syncthreads();

    // ---------- self MLP ----------
    if (tid < 50) {
        float a = t_b1[tid];
        #pragma unroll
        for (int i = 0; i < 16; ++i) a = fmaf(pacc[i], t_w1[i * 50 + tid], a);
        a0c[tid] = fmaxf(a, 0.f);                // hidden temp
    }
    __syncthreads();
    if (tid < 48) {                              // new_self -> X row0
        float a = t_b2[tid];
        for (int i = 0; i < 50; ++i) a = fmaf(a0c[i], t_w2[i * 48 + tid], a);
        unsigned short h, l; split2(fmaxf(a, 0.f), &h, &l);
        int o = (tid >> 4) * XP + (tid & 15);
        Xh[o] = h; Xl[o] = l;
    }
    if (tid >= 64 && tid < 128) pacc[tid - 64] = 0.f;     // p accumulator
    if (tid >= 128 && tid < 143) a0c[tid - 31] = 0.f;     // a0c[97..111] = 0
    __syncthreads();

    // ---------- step4 B-operand (X^T fragments) -> registers, ONCE ----------
    bf16x8 B4h[3], B4l[3];
    if (w < 3) {
        #pragma unroll
        for (int c3 = 0; c3 < 3; ++c3) {
            bf16x8 th, tl;
            #pragma unroll
            for (int j = 0; j < 8; ++j) {
                int e = w * XP + (32 * c3 + 8 * quad + j) * XS + row;
                th[j] = (short)Xh[e];
                tl[j] = (short)Xl[e];
            }
            B4h[c3] = th;
            B4l[c3] = tl;
        }
    } else {
        #pragma unroll
        for (int c3 = 0; c3 < 3; ++c3) { B4h[c3] = ZF; B4l[c3] = ZF; }
    }

    // ---------- prologue: step1(0) -> W0 ----------
    {
        if (w < 3) {
            f32x4 acc = {0.f, 0.f, 0.f, 0.f};
            #pragma unroll
            for (int ch = 0; ch < 2; ++ch) {
                int kb = 16 * ch;
                int c = kb + quad * 8;
                int o = (c >> 4) * XP + row * XS + (c & 15);
                bf16x8 ah = ldf(&Xh[o]);
                bf16x8 al = ldf(&Xl[o]);
                if (ch == 1 && quad < 2) { ah = ZF; al = ZF; }
                bf16x8 bh = ldf(waT_h + (16 * w + row) * 48 + kb + quad * 8);
                bf16x8 bl = ldf(waT_l + (16 * w + row) * 48 + kb + quad * 8);
                acc = __builtin_amdgcn_mfma_f32_16x16x32_bf16(ah, bh, acc, 0, 0, 0);
                acc = __builtin_amdgcn_mfma_f32_16x16x32_bf16(ah, bl, acc, 0, 0, 0);
                acc = __builtin_amdgcn_mfma_f32_16x16x32_bf16(al, bh, acc, 0, 0, 0);
            }
            #pragma unroll
            for (int r = 0; r < 4; ++r) {
                unsigned short h, l; split2(acc[r], &h, &l);
                W0h[(quad * 4 + r) * WS + 16 * w + row] = h;
                W0l[(quad * 4 + r) * WS + 16 * w + row] = l;
            }
        }
    }
    __syncthreads();
    // prologue: step2(0)+exp -> Eh, psum[0]; col-96 dot -> e96b[0], a0c[96]
    {
        bf16x8 a0h = ldf(&W0h[row * WS + quad * 8]);
        bf16x8 a0l = ldf(&W0l[row * WS + quad * 8]);
        bf16x8 a1h = ldf(&W0h[row * WS + 16 + quad * 8]);
        bf16x8 a1l = ldf(&W0l[row * WS + 16 + quad * 8]);
        if (quad < 2) { a1h = ZF; a1l = ZF; }
        float ps0 = 0.f, ps1 = 0.f, ps2 = 0.f, ps3 = 0.f;
        for (int t = w; t < 6; t += 4) {
            int m = 16 * t + row;
            f32x4 acc = {0.f, 0.f, 0.f, 0.f};
            int o0 = (quad >> 1) * XP + m * XS + (quad & 1) * 8;
            bf16x8 bh = ldf(&Xh[o0]);
            bf16x8 bl = ldf(&Xl[o0]);
            acc = __builtin_amdgcn_mfma_f32_16x16x32_bf16(a0h, bh, acc, 0, 0, 0);
            acc = __builtin_amdgcn_mfma_f32_16x16x32_bf16(a0h, bl, acc, 0, 0, 0);
            acc = __builtin_amdgcn_mfma_f32_16x16x32_bf16(a0l, bh, acc, 0, 0, 0);
            bh = ldf(&Xh[o0 + XP]);
            bl = ldf(&Xl[o0 + XP]);
            acc = __builtin_amdgcn_mfma_f32_16x16x32_bf16(a1h, bh, acc, 0, 0, 0);
            acc = __builtin_amdgcn_mfma_f32_16x16x32_bf16(a1h, bl, acc, 0, 0, 0);
            acc = __builtin_amdgcn_mfma_f32_16x16x32_bf16(a1l, bh, acc, 0, 0, 0);
            float e0v = __expf(acc[0]), e1v = __expf(acc[1]);
            float e2v = __expf(acc[2]), e3v = __expf(acc[3]);
            Eh[(quad * 4 + 0) * ES + m] = rtne16(e0v);
            Eh[(quad * 4 + 1) * ES + m] = rtne16(e1v);
            Eh[(quad * 4 + 2) * ES + m] = rtne16(e2v);
            Eh[(quad * 4 + 3) * ES + m] = rtne16(e3v);
            if (quad == 0) a0c[m] = e0v;          // row-0 numerators, fp32 unnorm
            ps0 += e0v; ps1 += e1v; ps2 += e2v; ps3 += e3v;
        }
        #pragma unroll
        for (int d = 1; d < 16; d <<= 1) {
            ps0 += __shfl_xor(ps0, d); ps1 += __shfl_xor(ps1, d);
            ps2 += __shfl_xor(ps2, d); ps3 += __shfl_xor(ps3, d);
        }
        if (row == 0) {
            psum[0][w * 16 + quad * 4 + 0] = ps0;
            psum[0][w * 16 + quad * 4 + 1] = ps1;
            psum[0][w * 16 + quad * 4 + 2] = ps2;
            psum[0][w * 16 + quad * 4 + 3] = ps3;
        }
        {   // col-96 dot for strip 0
            int rw = tid >> 4, mg = tid & 15;
            float s96 = 0.f;
            #pragma unroll
            for (int kk = 0; kk < 3; ++kk) {
                int c = mg + 16 * kk;
                float xw = bf2f(W0h[rw * WS + c]) + bf2f(W0l[rw * WS + c]);
                float xv = bf2f(Xh[kk * XP + 96 * XS + mg]) + bf2f(Xl[kk * XP + 96 * XS + mg]);
                s96 = fmaf(xw, xv, s96);
            }
            s96 += __shfl_xor(s96, 1); s96 += __shfl_xor(s96, 2);
            s96 += __shfl_xor(s96, 4); s96 += __shfl_xor(s96, 8);
            if (mg == 0) {
                float e0 = __expf(s96);
                e96b[0][rw] = e0;
                if (rw == 0) a0c[96] = e0;
            }
        }
    }
    __syncthreads();

    // ---------- pipelined strip loop: 2 barriers/strip ----------
    for (int s = 0; s < 7; ++s) {
        unsigned short* Wsh = (s & 1) ? W1h : W0h;   // this strip (Xw dead -> AXu)
        unsigned short* Wsl = (s & 1) ? W1l : W0l;
        unsigned short* Wnh = (s & 1) ? W0h : W1h;   // next strip's Xw
        unsigned short* Wnl = (s & 1) ? W0l : W1l;
        const int sb_ = s & 1;

        // ---- phase AB: w<3: step4(s) unnorm + step1(s+1); w3: invb ----
        if (w < 3) {
            {   // step4(s): AXu = E@X + e96*X96 (NO invb)
                f32x4 acc = {0.f, 0.f, 0.f, 0.f};
                #pragma unroll
                for (int c3 = 0; c3 < 3; ++c3) {
                    int mb = 32 * c3;
                    bf16x8 ah = ldf(&Eh[row * ES + mb + quad * 8]);
                    acc = __builtin_amdgcn_mfma_f32_16x16x32_bf16(ah, B4h[c3], acc, 0, 0, 0);
                    acc = __builtin_amdgcn_mfma_f32_16x16x32_bf16(ah, B4l[c3], acc, 0, 0, 0);
                }
                int j = 16 * w + row;
                float xv = bf2f(Xh[w * XP + 96 * XS + row]) + bf2f(Xl[w * XP + 96 * XS + row]);
                #pragma unroll
                for (int r = 0; r < 4; ++r) {
                    float v = fmaf(e96b[sb_][quad * 4 + r], xv, acc[r]);
                    unsigned short h, l; split2(v, &h, &l);
                    Wsh[(quad * 4 + r) * WS + j] = h;
                    Wsl[(quad * 4 + r) * WS + j] = l;
                }
            }
            if (s < 6) {   // step1(s+1) -> Wn
                f32x4 acc = {0.f, 0.f, 0.f, 0.f};
                int n = (s + 1) * 16 + row; int nc = n < 97 ? n : 96;  // strip-6 tail
                #pragma unroll
                for (int ch = 0; ch < 2; ++ch) {
                    int kb = 16 * ch;
                    int c = kb + quad * 8;
                    int o = (c >> 4) * XP + nc * XS + (c & 15);
                    bf16x8 ah = ldf(&Xh[o]);
                    bf16x8 al = ldf(&Xl[o]);
                    if (ch == 1 && quad < 2) { ah = ZF; al = ZF; }
                    bf16x8 bh = ldf(waT_h + (16 * w + row) * 48 + kb + quad * 8);
                    bf16x8 bl = ldf(waT_l + (16 * w + row) * 48 + kb + quad * 8);
                    acc = __builtin_amdgcn_mfma_f32_16x16x32_bf16(ah, bh, acc, 0, 0, 0);
                    acc = __builtin_amdgcn_mfma_f32_16x16x32_bf16(ah, bl, acc, 0, 0, 0);
                    acc = __builtin_amdgcn_mfma_f32_16x16x32_bf16(al, bh, acc, 0, 0, 0);
                }
                #pragma unroll
                for (int r = 0; r < 4; ++r) {
                    unsigned short h, l; split2(acc[r], &h, &l);
                    Wnh[(quad * 4 + r) * WS + 16 * w + row] = h;
                    Wnl[(quad * 4 + r) * WS + 16 * w + row] = l;
                }
            }
        } else {
            if (lane < 16) {   // invb(s) from pre-barrier psum/e96
                float sden = psum[sb_][lane] + psum[sb_][16 + lane]
                           + psum[sb_][32 + lane] + psum[sb_][48 + lane]
                           + e96b[sb_][lane];
                float iv = 1.f / sden;
                invbS[lane] = iv;
                if (s == 0 && lane == 0) inv0s = iv;
            }
        }
        __syncthreads();

        // ---- phase C: step5(s) [invb post-relu] + step2(s+1)+exp + dot ----
        {   // h1 = invb*relu(AXu @ w1); p += a0u-weighted rows
            f32x4 acc = {0.f, 0.f, 0.f, 0.f};
            #pragma unroll
            for (int ch = 0; ch < 2; ++ch) {
                int kb = 16 * ch;
                bf16x8 ah = ldf(&Wsh[row * WS + kb + quad * 8]);
                bf16x8 al = ldf(&Wsl[row * WS + kb + quad * 8]);
                if (ch == 1 && quad < 2) { ah = ZF; al = ZF; }
                bf16x8 bh = ldf(w1T_h + (16 * w + row) * 48 + kb + quad * 8);
                bf16x8 bl = ldf(w1T_l + (16 * w + row) * 48 + kb + quad * 8);
                acc = __builtin_amdgcn_mfma_f32_16x16x32_bf16(ah, bh, acc, 0, 0, 0);
                acc = __builtin_amdgcn_mfma_f32_16x16x32_bf16(ah, bl, acc, 0, 0, 0);
                acc = __builtin_amdgcn_mfma_f32_16x16x32_bf16(al, bh, acc, 0, 0, 0);
            }
            float part = 0.f;
            #pragma unroll
            for (int r = 0; r < 4; ++r) {
                int n = quad * 4 + r;
                part += fmaxf(acc[r], 0.f) * (a0c[s * 16 + n] * invbS[n]);
            }
            part += __shfl_xor(part, 16);
            part += __shfl_xor(part, 32);
            if (quad == 0) pacc[16 * w + row] += part;
        }
        if (s < 6) {   // step2(s+1)+exp -> Eh, psum[(s+1)&1]; dot -> e96b[(s+1)&1]
            bf16x8 a0h = ldf(&Wnh[row * WS + quad * 8]);
            bf16x8 a0l = ldf(&Wnl[row * WS + quad * 8]);
            bf16x8 a1h = ldf(&Wnh[row * WS + 16 + quad * 8]);
            bf16x8 a1l = ldf(&Wnl[row * WS + 16 + quad * 8]);
            if (quad < 2) { a1h = ZF; a1l = ZF; }
            float ps0 = 0.f, ps1 = 0.f, ps2 = 0.f, ps3 = 0.f;
            for (int t = w; t < 6; t += 4) {
                int m = 16 * t + row;
                f32x4 acc = {0.f, 0.f, 0.f, 0.f};
                int o0 = (quad >> 1) * XP + m * XS + (quad & 1) * 8;
                bf16x8 bh = ldf(&Xh[o0]);
                bf16x8 bl = ldf(&Xl[o0]);
                acc = __builtin_amdgcn_mfma_f32_16x16x32_bf16(a0h, bh, acc, 0, 0, 0);
                acc = __builtin_amdgcn_mfma_f32_16x16x32_bf16(a0h, bl, acc, 0, 0, 0);
                acc = __builtin_amdgcn_mfma_f32_16x16x32_bf16(a0l, bh, acc, 0, 0, 0);
                bh = ldf(&Xh[o0 + XP]);
                bl = ldf(&Xl[o0 + XP]);
                acc = __builtin_amdgcn_mfma_f32_16x16x32_bf16(a1h, bh, acc, 0, 0, 0);
                acc = __builtin_amdgcn_mfma_f32_16x16x32_bf16(a1h, bl, acc, 0, 0, 0);
                acc = __builtin_amdgcn_mfma_f32_16x16x32_bf16(a1l, bh, acc, 0, 0, 0);
                float e0v = __expf(acc[0]), e1v = __expf(acc[1]);
                float e2v = __expf(acc[2]), e3v = __expf(acc[3]);
                Eh[(quad * 4 + 0) * ES + m] = rtne16(e0v);
                Eh[(quad * 4 + 1) * ES + m] = rtne16(e1v);
                Eh[(quad * 4 + 2) * ES + m] = rtne16(e2v);
                Eh[(quad * 4 + 3) * ES + m] = rtne16(e3v);
                ps0 += e0v; ps1 += e1v; ps2 += e2v; ps3 += e3v;
            }
            #pragma unroll
            for (int d = 1; d < 16; d <<= 1) {
                ps0 += __shfl_xor(ps0, d); ps1 += __shfl_xor(ps1, d);
                ps2 += __shfl_xor(ps2, d); ps3 += __shfl_xor(ps3, d);
            }
            const int nb2 = (s + 1) & 1;
            if (row == 0) {
                psum[nb2][w * 16 + quad * 4 + 0] = ps0;
                psum[nb2][w * 16 + quad * 4 + 1] = ps1;
                psum[nb2][w * 16 + quad * 4 + 2] = ps2;
                psum[nb2][w * 16 + quad * 4 + 3] = ps3;
            }
            {   // col-96 dot for strip s+1
                int rw = tid >> 4, mg = tid & 15;
                float s96 = 0.f;
                #pragma unroll
                for (int kk = 0; kk < 3; ++kk) {
                    int c = mg + 16 * kk;
                    float xw = bf2f(Wnh[rw * WS + c]) + bf2f(Wnl[rw * WS + c]);
                    float xv = bf2f(Xh[kk * XP + 96 * XS + mg]) + bf2f(Xl[kk * XP + 96 * XS + mg]);
                    s96 = fmaf(xw, xv, s96);
                }
                s96 += __shfl_xor(s96, 1); s96 += __shfl_xor(s96, 2);
                s96 += __shfl_xor(s96, 4); s96 += __shfl_xor(s96, 8);
                if (mg == 0) e96b[nb2][rw] = __expf(s96);
            }
        }
        __syncthreads();
    }

    // ---------- head (featb overlaid on a0c; a0c dead) ----------
    float* featb = a0c;
    if (tid < 64) {
        float a = 0.f;
        #pragma unroll 8
        for (int l = 0; l < 64; ++l) a = fmaf(pacc[l], w2[l * 64 + tid], a);
        featb[tid] = fmaxf(a * inv0s, 0.f);      // fold A-row-0 1/sum here
    }
    __syncthreads();
    if (tid < 64) {
        float a = v_b1[tid];
        #pragma unroll 8
        for (int c = 0; c < 64; ++c) a = fmaf(featb[c], v_w1[c * 64 + tid], a);
        float qd = fmaxf(a, 0.f) * v_w2[tid];
        #pragma unroll
        for (int d = 32; d >= 1; d >>= 1) qd += __shfl_xor(qd, d);
        if (tid == 0) out[b] = qd + v_b2[0];
    }
}

extern "C" void kernel_launch(void* const* d_in, const int* in_sizes, int n_in,
                              void* d_out, int out_size, void* d_ws, size_t ws_size,
                              hipStream_t stream) {
    (void)n_in; (void)ws_size; (void)out_size;
    const float* state = (const float*)d_in[0];
    const float* t_w1  = (const float*)d_in[1];
    const float* t_b1  = (const float*)d_in[2];
    const float* t_w2  = (const float*)d_in[3];
    const float* t_b2  = (const float*)d_in[4];
    const float* w_a   = (const float*)d_in[5];
    const float* w1    = (const float*)d_in[6];
    const float* w2    = (const float*)d_in[7];
    const float* v_w1  = (const float*)d_in[8];
    const float* v_b1  = (const float*)d_in[9];
    const float* v_w2  = (const float*)d_in[10];
    const float* v_b2  = (const float*)d_in[11];
    unsigned short* ws = (unsigned short*)d_ws;
    const int nb = in_sizes[0] / (96 * 64);   // 8192

    vnet_prep<<<1, 256, 0, stream>>>(w_a, w1, ws);
    vnet_kernel<<<nb, 256, 0, stream>>>(state, t_w1, t_b1, t_w2, t_b2, w2,
                                        v_w1, v_b1, v_w2, v_b2, ws, (float*)d_out);
}

// Round 8
// 437.429 us; speedup vs baseline: 1.0451x; 1.0451x over previous
//
#include <hip/hip_runtime.h>

// ValueNetwork B=8192, rows=97 (1 self + 96 human), HUMAN_DIM=48.
// One block (256 thr) per batch. GEMMs on MFMA 16x16x32 bf16 hi/lo split.
// R11: revert R10's XS=24 (bank conflicts +50%, 2.5%-of-runtime red herring);
// W planes (Xw / AXu) now SINGLE bf16 (lo deleted). Phase C MFMA 18->12 on
// busy waves (step2 12->8, step5 6->4); step1/step4 outputs rtne16+1 store
// (was split2+2); W0l/W1l deleted -> LDS ~27.1KB -> 5-6 blocks/CU.
// Error: +2^-9 rel on S (Xw) and h1 (AXu); R7 datapoint says ~+1.2e-4 each
// at out -> predicted absmax 3.5-6e-4 vs 9.375e-4 threshold.
// X, waT, w1T stay hi/lo. R9 2-barrier structure otherwise unchanged.

#define XP (97 * 16)  // ushorts per X column-panel (row stride 16)
#define ES 104        // E plane row stride (ushort)
#define WS 56         // W (Xw/AXu) plane row stride (ushort)

typedef short bf16x8 __attribute__((ext_vector_type(8)));
typedef float f32x4 __attribute__((ext_vector_type(4)));

__device__ __forceinline__ unsigned rtne_hi(float f) {
    unsigned u = __float_as_uint(f);
    return (u + 0x7fffu + ((u >> 16) & 1u)) & 0xffff0000u;
}
__device__ __forceinline__ void split2(float f, unsigned short* h, unsigned short* l) {
    unsigned hb = rtne_hi(f);
    float r = f - __uint_as_float(hb);
    *h = (unsigned short)(hb >> 16);
    *l = (unsigned short)(__float_as_uint(r) >> 16);
}
__device__ __forceinline__ unsigned short rtne16(float f) {
    return (unsigned short)(rtne_hi(f) >> 16);
}
__device__ __forceinline__ float bf2f(unsigned short u) {
    return __uint_as_float(((unsigned)u) << 16);
}
__device__ __forceinline__ bf16x8 ldf(const unsigned short* p) {
    return *(const bf16x8*)p;
}

__global__ void vnet_prep(const float* __restrict__ w_a, const float* __restrict__ w1,
                          unsigned short* __restrict__ ws) {
    unsigned short* waT_h = ws;                 // waT[c][k] = w_a[k][c], 48x48
    unsigned short* waT_l = ws + 2304;
    unsigned short* w1T_h = ws + 4608;          // w1T[l][j] = w1[j][l], 64x48
    unsigned short* w1T_l = ws + 4608 + 3072;
    for (int i = threadIdx.x; i < 48 * 48; i += blockDim.x) {
        int c = i / 48, k = i % 48;
        unsigned short h, l; split2(w_a[k * 48 + c], &h, &l);
        waT_h[i] = h; waT_l[i] = l;
    }
    for (int i = threadIdx.x; i < 64 * 48; i += blockDim.x) {
        int lo = i / 48, j = i % 48;
        unsigned short h, l; split2(w1[j * 64 + lo], &h, &l);
        w1T_h[i] = h; w1T_l[i] = l;
    }
}

__global__ __launch_bounds__(256, 4)
void vnet_kernel(const float* __restrict__ state,
                 const float* __restrict__ t_w1, const float* __restrict__ t_b1,
                 const float* __restrict__ t_w2, const float* __restrict__ t_b2,
                 const float* __restrict__ w2,   const float* __restrict__ v_w1,
                 const float* __restrict__ v_b1, const float* __restrict__ v_w2,
                 const float* __restrict__ v_b2, const unsigned short* __restrict__ ws,
                 float* __restrict__ out)
{
    __shared__ __align__(16) unsigned short Xh[3 * XP], Xl[3 * XP];       // 9312 B each
    __shared__ __align__(16) unsigned short Eh[16 * ES];                  // 3328 B (E single)
    __shared__ __align__(16) unsigned short W0h[16 * WS], W1h[16 * WS];   // 1792 B each (single)
    __shared__ float a0c[112];     // A row 0 numerators (UNNORMALIZED); [97..111]=0
    __shared__ float e96b[2][16];  // double-buffered exp(S[n][96]) per strip
    __shared__ float psum[2][64];  // double-buffered per-wave row sums [buf][w*16+n]
    __shared__ float invbS[16];    // per-strip 1/rowsum (written by wave 3 in AB)
    __shared__ float pacc[64];     // p accumulator; [0..15] self-state temp at setup
    __shared__ float inv0s;        // 1/rowsum of strip0 row0 (head factor)

    const unsigned short* waT_h = ws;
    const unsigned short* waT_l = ws + 2304;
    const unsigned short* w1T_h = ws + 4608;
    const unsigned short* w1T_l = ws + 4608 + 3072;

    const int tid  = threadIdx.x;
    const int w    = tid >> 6;
    const int lane = tid & 63;
    const int row  = lane & 15;
    const int quad = lane >> 4;
    const int b    = blockIdx.x;
    const float* sb = state + (size_t)b * (96 * 64);
    const bf16x8 ZF = {0, 0, 0, 0, 0, 0, 0, 0};

    // ---------- stage X rows 1..96 into column panels ----------
    if (tid < 16) pacc[tid] = sb[tid];           // self-state temp
    for (int i = tid; i < 96 * 12; i += 256) {
        int r = i / 12, q = i % 12;
        float4 v = *(const float4*)(sb + r * 64 + 16 + 4 * q);
        unsigned short h0, l0, h1v, l1, h2, l2, h3, l3;
        split2(v.x, &h0, &l0); split2(v.y, &h1v, &l1);
        split2(v.z, &h2, &l2); split2(v.w, &h3, &l3);
        int m = 1 + r;
        int o = (q >> 2) * XP + m * 16 + (q & 3) * 4;
        *(uint2*)&Xh[o] = make_uint2((unsigned)h0 | ((unsigned)h1v << 16),
                                     (unsigned)h2 | ((unsigned)h3 << 16));
        *(uint2*)&Xl[o] = make_uint2((unsigned)l0 | ((unsigned)l1 << 16),
                                     (unsigned)l2 | ((unsigned)l3 << 16));
    }
    __syncthreads();

    // ---------- self MLP ----------
    if (tid < 50) {
        float a = t_b1[tid];
        #pragma unroll
        for (int i = 0; i < 16; ++i) a = fmaf(pacc[i], t_w1[i * 50 + tid], a);
        a0c[tid] = fmaxf(a, 0.f);                // hidden temp
    }
    __syncthreads();
    if (tid < 48) {                              // new_self -> X row0
        float a = t_b2[tid];
        for (int i = 0; i < 50; ++i) a = fmaf(a0c[i], t_w2[i * 48 + tid], a);
        unsigned short h, l; split2(fmaxf(a, 0.f), &h, &l);
        int o = (tid >> 4) * XP + (tid & 15);
        Xh[o] = h; Xl[o] = l;
    }
    if (tid >= 64 && tid < 128) pacc[tid - 64] = 0.f;     // p accumulator
    if (tid >= 128 && tid < 143) a0c[tid - 31] = 0.f;     // a0c[97..111] = 0
    __syncthreads();

    // ---------- step4 B-operand (X^T fragments) -> registers, ONCE ----------
    bf16x8 B4h[3], B4l[3];
    if (w < 3) {
        #pragma unroll
        for (int c3 = 0; c3 < 3; ++c3) {
            bf16x8 th, tl;
            #pragma unroll
            for (int j = 0; j < 8; ++j) {
                int e = w * XP + (32 * c3 + 8 * quad + j) * 16 + row;
                th[j] = (short)Xh[e];
                tl[j] = (short)Xl[e];
            }
            B4h[c3] = th;
            B4l[c3] = tl;
        }
    } else {
        #pragma unroll
        for (int c3 = 0; c3 < 3; ++c3) { B4h[c3] = ZF; B4l[c3] = ZF; }
    }

    // ---------- prologue: step1(0) -> W0 (single plane) ----------
    {
        if (w < 3) {
            f32x4 acc = {0.f, 0.f, 0.f, 0.f};
            #pragma unroll
            for (int ch = 0; ch < 2; ++ch) {
                int kb = 16 * ch;
                int c = kb + quad * 8;
                int o = (c >> 4) * XP + row * 16 + (c & 15);
                bf16x8 ah = ldf(&Xh[o]);
                bf16x8 al = ldf(&Xl[o]);
                if (ch == 1 && quad < 2) { ah = ZF; al = ZF; }
                bf16x8 bh = ldf(waT_h + (16 * w + row) * 48 + kb + quad * 8);
                bf16x8 bl = ldf(waT_l + (16 * w + row) * 48 + kb + quad * 8);
                acc = __builtin_amdgcn_mfma_f32_16x16x32_bf16(ah, bh, acc, 0, 0, 0);
                acc = __builtin_amdgcn_mfma_f32_16x16x32_bf16(ah, bl, acc, 0, 0, 0);
                acc = __builtin_amdgcn_mfma_f32_16x16x32_bf16(al, bh, acc, 0, 0, 0);
            }
            #pragma unroll
            for (int r = 0; r < 4; ++r)
                W0h[(quad * 4 + r) * WS + 16 * w + row] = rtne16(acc[r]);
        }
    }
    __syncthreads();
    // prologue: step2(0)+exp -> Eh, psum[0]; col-96 dot -> e96b[0], a0c[96]
    {
        bf16x8 a0h = ldf(&W0h[row * WS + quad * 8]);
        bf16x8 a1h = ldf(&W0h[row * WS + 16 + quad * 8]);
        if (quad < 2) a1h = ZF;
        float ps0 = 0.f, ps1 = 0.f, ps2 = 0.f, ps3 = 0.f;
        for (int t = w; t < 6; t += 4) {
            int m = 16 * t + row;
            f32x4 acc = {0.f, 0.f, 0.f, 0.f};
            int o0 = (quad >> 1) * XP + m * 16 + (quad & 1) * 8;
            bf16x8 bh = ldf(&Xh[o0]);
            bf16x8 bl = ldf(&Xl[o0]);
            acc = __builtin_amdgcn_mfma_f32_16x16x32_bf16(a0h, bh, acc, 0, 0, 0);
            acc = __builtin_amdgcn_mfma_f32_16x16x32_bf16(a0h, bl, acc, 0, 0, 0);
            bh = ldf(&Xh[o0 + XP]);
            bl = ldf(&Xl[o0 + XP]);
            acc = __builtin_amdgcn_mfma_f32_16x16x32_bf16(a1h, bh, acc, 0, 0, 0);
            acc = __builtin_amdgcn_mfma_f32_16x16x32_bf16(a1h, bl, acc, 0, 0, 0);
            float e0v = __expf(acc[0]), e1v = __expf(acc[1]);
            float e2v = __expf(acc[2]), e3v = __expf(acc[3]);
            Eh[(quad * 4 + 0) * ES + m] = rtne16(e0v);
            Eh[(quad * 4 + 1) * ES + m] = rtne16(e1v);
            Eh[(quad * 4 + 2) * ES + m] = rtne16(e2v);
            Eh[(quad * 4 + 3) * ES + m] = rtne16(e3v);
            if (quad == 0) a0c[m] = e0v;          // row-0 numerators, fp32 unnorm
            ps0 += e0v; ps1 += e1v; ps2 += e2v; ps3 += e3v;
        }
        #pragma unroll
        for (int d = 1; d < 16; d <<= 1) {
            ps0 += __shfl_xor(ps0, d); ps1 += __shfl_xor(ps1, d);
            ps2 += __shfl_xor(ps2, d); ps3 += __shfl_xor(ps3, d);
        }
        if (row == 0) {
            psum[0][w * 16 + quad * 4 + 0] = ps0;
            psum[0][w * 16 + quad * 4 + 1] = ps1;
            psum[0][w * 16 + quad * 4 + 2] = ps2;
            psum[0][w * 16 + quad * 4 + 3] = ps3;
        }
        {   // col-96 dot for strip 0
            int rw = tid >> 4, mg = tid & 15;
            float s96 = 0.f;
            #pragma unroll
            for (int kk = 0; kk < 3; ++kk) {
                int c = mg + 16 * kk;
                float xw = bf2f(W0h[rw * WS + c]);
                float xv = bf2f(Xh[kk * XP + 1536 + mg]) + bf2f(Xl[kk * XP + 1536 + mg]);
                s96 = fmaf(xw, xv, s96);
            }
            s96 += __shfl_xor(s96, 1); s96 += __shfl_xor(s96, 2);
            s96 += __shfl_xor(s96, 4); s96 += __shfl_xor(s96, 8);
            if (mg == 0) {
                float e0 = __expf(s96);
                e96b[0][rw] = e0;
                if (rw == 0) a0c[96] = e0;
            }
        }
    }
    __syncthreads();

    // ---------- pipelined strip loop: 2 barriers/strip ----------
    for (int s = 0; s < 7; ++s) {
        unsigned short* Wsh = (s & 1) ? W1h : W0h;   // this strip (Xw dead -> AXu)
        unsigned short* Wnh = (s & 1) ? W0h : W1h;   // next strip's Xw
        const int sb_ = s & 1;

        // ---- phase AB: w<3: step4(s) unnorm + step1(s+1); w3: invb ----
        if (w < 3) {
            {   // step4(s): AXu = E@X + e96*X96 (NO invb), single-plane out
                f32x4 acc = {0.f, 0.f, 0.f, 0.f};
                #pragma unroll
                for (int c3 = 0; c3 < 3; ++c3) {
                    int mb = 32 * c3;
                    bf16x8 ah = ldf(&Eh[row * ES + mb + quad * 8]);
                    acc = __builtin_amdgcn_mfma_f32_16x16x32_bf16(ah, B4h[c3], acc, 0, 0, 0);
                    acc = __builtin_amdgcn_mfma_f32_16x16x32_bf16(ah, B4l[c3], acc, 0, 0, 0);
                }
                int j = 16 * w + row;
                float xv = bf2f(Xh[w * XP + 1536 + row]) + bf2f(Xl[w * XP + 1536 + row]);
                #pragma unroll
                for (int r = 0; r < 4; ++r) {
                    float v = fmaf(e96b[sb_][quad * 4 + r], xv, acc[r]);
                    Wsh[(quad * 4 + r) * WS + j] = rtne16(v);
                }
            }
            if (s < 6) {   // step1(s+1) -> Wn (single plane)
                f32x4 acc = {0.f, 0.f, 0.f, 0.f};
                int n = (s + 1) * 16 + row; int nc = n < 97 ? n : 96;  // strip-6 tail
                #pragma unroll
                for (int ch = 0; ch < 2; ++ch) {
                    int kb = 16 * ch;
                    int c = kb + quad * 8;
                    int o = (c >> 4) * XP + nc * 16 + (c & 15);
                    bf16x8 ah = ldf(&Xh[o]);
                    bf16x8 al = ldf(&Xl[o]);
                    if (ch == 1 && quad < 2) { ah = ZF; al = ZF; }
                    bf16x8 bh = ldf(waT_h + (16 * w + row) * 48 + kb + quad * 8);
                    bf16x8 bl = ldf(waT_l + (16 * w + row) * 48 + kb + quad * 8);
                    acc = __builtin_amdgcn_mfma_f32_16x16x32_bf16(ah, bh, acc, 0, 0, 0);
                    acc = __builtin_amdgcn_mfma_f32_16x16x32_bf16(ah, bl, acc, 0, 0, 0);
                    acc = __builtin_amdgcn_mfma_f32_16x16x32_bf16(al, bh, acc, 0, 0, 0);
                }
                #pragma unroll
                for (int r = 0; r < 4; ++r)
                    Wnh[(quad * 4 + r) * WS + 16 * w + row] = rtne16(acc[r]);
            }
        } else {
            if (lane < 16) {   // invb(s) from pre-barrier psum/e96
                float sden = psum[sb_][lane] + psum[sb_][16 + lane]
                           + psum[sb_][32 + lane] + psum[sb_][48 + lane]
                           + e96b[sb_][lane];
                float iv = 1.f / sden;
                invbS[lane] = iv;
                if (s == 0 && lane == 0) inv0s = iv;
            }
        }
        __syncthreads();

        // ---- phase C: step5(s) [invb post-relu] + step2(s+1)+exp + dot ----
        {   // h1 = invb*relu(AXu @ w1); p += a0u-weighted rows
            f32x4 acc = {0.f, 0.f, 0.f, 0.f};
            #pragma unroll
            for (int ch = 0; ch < 2; ++ch) {
                int kb = 16 * ch;
                bf16x8 ah = ldf(&Wsh[row * WS + kb + quad * 8]);
                if (ch == 1 && quad < 2) ah = ZF;
                bf16x8 bh = ldf(w1T_h + (16 * w + row) * 48 + kb + quad * 8);
                bf16x8 bl = ldf(w1T_l + (16 * w + row) * 48 + kb + quad * 8);
                acc = __builtin_amdgcn_mfma_f32_16x16x32_bf16(ah, bh, acc, 0, 0, 0);
                acc = __builtin_amdgcn_mfma_f32_16x16x32_bf16(ah, bl, acc, 0, 0, 0);
            }
            float part = 0.f;
            #pragma unroll
            for (int r = 0; r < 4; ++r) {
                int n = quad * 4 + r;
                part += fmaxf(acc[r], 0.f) * (a0c[s * 16 + n] * invbS[n]);
            }
            part += __shfl_xor(part, 16);
            part += __shfl_xor(part, 32);
            if (quad == 0) pacc[16 * w + row] += part;
        }
        if (s < 6) {   // step2(s+1)+exp -> Eh, psum[(s+1)&1]; dot -> e96b[(s+1)&1]
            bf16x8 a0h = ldf(&Wnh[row * WS + quad * 8]);
            bf16x8 a1h = ldf(&Wnh[row * WS + 16 + quad * 8]);
            if (quad < 2) a1h = ZF;
            float ps0 = 0.f, ps1 = 0.f, ps2 = 0.f, ps3 = 0.f;
            for (int t = w; t < 6; t += 4) {
                int m = 16 * t + row;
                f32x4 acc = {0.f, 0.f, 0.f, 0.f};
                int o0 = (quad >> 1) * XP + m * 16 + (quad & 1) * 8;
                bf16x8 bh = ldf(&Xh[o0]);
                bf16x8 bl = ldf(&Xl[o0]);
                acc = __builtin_amdgcn_mfma_f32_16x16x32_bf16(a0h, bh, acc, 0, 0, 0);
                acc = __builtin_amdgcn_mfma_f32_16x16x32_bf16(a0h, bl, acc, 0, 0, 0);
                bh = ldf(&Xh[o0 + XP]);
                bl = ldf(&Xl[o0 + XP]);
                acc = __builtin_amdgcn_mfma_f32_16x16x32_bf16(a1h, bh, acc, 0, 0, 0);
                acc = __builtin_amdgcn_mfma_f32_16x16x32_bf16(a1h, bl, acc, 0, 0, 0);
                float e0v = __expf(acc[0]), e1v = __expf(acc[1]);
                float e2v = __expf(acc[2]), e3v = __expf(acc[3]);
                Eh[(quad * 4 + 0) * ES + m] = rtne16(e0v);
                Eh[(quad * 4 + 1) * ES + m] = rtne16(e1v);
                Eh[(quad * 4 + 2) * ES + m] = rtne16(e2v);
                Eh[(quad * 4 + 3) * ES + m] = rtne16(e3v);
                ps0 += e0v; ps1 += e1v; ps2 += e2v; ps3 += e3v;
            }
            #pragma unroll
            for (int d = 1; d < 16; d <<= 1) {
                ps0 += __shfl_xor(ps0, d); ps1 += __shfl_xor(ps1, d);
                ps2 += __shfl_xor(ps2, d); ps3 += __shfl_xor(ps3, d);
            }
            const int nb2 = (s + 1) & 1;
            if (row == 0) {
                psum[nb2][w * 16 + quad * 4 + 0] = ps0;
                psum[nb2][w * 16 + quad * 4 + 1] = ps1;
                psum[nb2][w * 16 + quad * 4 + 2] = ps2;
                psum[nb2][w * 16 + quad * 4 + 3] = ps3;
            }
            {   // col-96 dot for strip s+1
                int rw = tid >> 4, mg = tid & 15;
                float s96 = 0.f;
                #pragma unroll
                for (int kk = 0; kk < 3; ++kk) {
                    int c = mg + 16 * kk;
                    float xw = bf2f(Wnh[rw * WS + c]);
                    float xv = bf2f(Xh[kk * XP + 1536 + mg]) + bf2f(Xl[kk * XP + 1536 + mg]);
                    s96 = fmaf(xw, xv, s96);
                }
                s96 += __shfl_xor(s96, 1); s96 += __shfl_xor(s96, 2);
                s96 += __shfl_xor(s96, 4); s96 += __shfl_xor(s96, 8);
                if (mg == 0) e96b[nb2][rw] = __expf(s96);
            }
        }
        __syncthreads();
    }

    // ---------- head (featb overlaid on a0c; a0c dead) ----------
    float* featb = a0c;
    if (tid < 64) {
        float a = 0.f;
        #pragma unroll 8
        for (int l = 0; l < 64; ++l) a = fmaf(pacc[l], w2[l * 64 + tid], a);
        featb[tid] = fmaxf(a * inv0s, 0.f);      // fold A-row-0 1/sum here
    }
    __syncthreads();
    if (tid < 64) {
        float a = v_b1[tid];
        #pragma unroll 8
        for (int c = 0; c < 64; ++c) a = fmaf(featb[c], v_w1[c * 64 + tid], a);
        float qd = fmaxf(a, 0.f) * v_w2[tid];
        #pragma unroll
        for (int d = 32; d >= 1; d >>= 1) qd += __shfl_xor(qd, d);
        if (tid == 0) out[b] = qd + v_b2[0];
    }
}

extern "C" void kernel_launch(void* const* d_in, const int* in_sizes, int n_in,
                              void* d_out, int out_size, void* d_ws, size_t ws_size,
                              hipStream_t stream) {
    (void)n_in; (void)ws_size; (void)out_size;
    const float* state = (const float*)d_in[0];
    const float* t_w1  = (const float*)d_in[1];
    const float* t_b1  = (const float*)d_in[2];
    const float* t_w2  = (const float*)d_in[3];
    const float* t_b2  = (const float*)d_in[4];
    const float* w_a   = (const float*)d_in[5];
    const float* w1    = (const float*)d_in[6];
    const float* w2    = (const float*)d_in[7];
    const float* v_w1  = (const float*)d_in[8];
    const float* v_b1  = (const float*)d_in[9];
    const float* v_w2  = (const float*)d_in[10];
    const float* v_b2  = (const float*)d_in[11];
    unsigned short* ws = (unsigned short*)d_ws;
    const int nb = in_sizes[0] / (96 * 64);   // 8192

    vnet_prep<<<1, 256, 0, stream>>>(w_a, w1, ws);
    vnet_kernel<<<nb, 256, 0, stream>>>(state, t_w1, t_b1, t_w2, t_b2, w2,
                                        v_w1, v_b1, v_w2, v_b2, ws, (float*)d_out);
}

// Round 9
// 410.780 us; speedup vs baseline: 1.1129x; 1.0649x over previous
//
#include <hip/hip_runtime.h>

// ValueNetwork B=8192, rows=97 (1 self + 96 human), HUMAN_DIM=48.
// One block (256 thr) per batch. GEMMs on MFMA 16x16x32 bf16 hi/lo split.
// R12 "C-phase diet": psum+butterfly DELETED — wave 3 (idle in AB) sums the
// softmax denominators directly from Eh (4 lanes/row, 3x b128 + 24 adds) and
// precomputes a0w[n]=a0c[s*16+n]*invb[n]; col-96 dot moves to waves 2-3 only
// (8 lanes/row). Phase C loses ~50 inst/thread on the busy waves. Denominator
// now sums ROUNDED E (the values step4 actually uses) — negligible delta.
// R11 content kept: W single-plane, 2-barrier strip loop, unnorm step4 +
// post-relu invb, exp fused in step2, E single-plane, X panels hi/lo.

#define XP (97 * 16)  // ushorts per X column-panel (row stride 16)
#define ES 104        // E plane row stride (ushort)
#define WS 56         // W (Xw/AXu) plane row stride (ushort)

typedef short bf16x8 __attribute__((ext_vector_type(8)));
typedef float f32x4 __attribute__((ext_vector_type(4)));

__device__ __forceinline__ unsigned rtne_hi(float f) {
    unsigned u = __float_as_uint(f);
    return (u + 0x7fffu + ((u >> 16) & 1u)) & 0xffff0000u;
}
__device__ __forceinline__ void split2(float f, unsigned short* h, unsigned short* l) {
    unsigned hb = rtne_hi(f);
    float r = f - __uint_as_float(hb);
    *h = (unsigned short)(hb >> 16);
    *l = (unsigned short)(__float_as_uint(r) >> 16);
}
__device__ __forceinline__ unsigned short rtne16(float f) {
    return (unsigned short)(rtne_hi(f) >> 16);
}
__device__ __forceinline__ float bf2f(unsigned short u) {
    return __uint_as_float(((unsigned)u) << 16);
}
__device__ __forceinline__ bf16x8 ldf(const unsigned short* p) {
    return *(const bf16x8*)p;
}

__global__ void vnet_prep(const float* __restrict__ w_a, const float* __restrict__ w1,
                          unsigned short* __restrict__ ws) {
    unsigned short* waT_h = ws;                 // waT[c][k] = w_a[k][c], 48x48
    unsigned short* waT_l = ws + 2304;
    unsigned short* w1T_h = ws + 4608;          // w1T[l][j] = w1[j][l], 64x48
    unsigned short* w1T_l = ws + 4608 + 3072;
    for (int i = threadIdx.x; i < 48 * 48; i += blockDim.x) {
        int c = i / 48, k = i % 48;
        unsigned short h, l; split2(w_a[k * 48 + c], &h, &l);
        waT_h[i] = h; waT_l[i] = l;
    }
    for (int i = threadIdx.x; i < 64 * 48; i += blockDim.x) {
        int lo = i / 48, j = i % 48;
        unsigned short h, l; split2(w1[j * 64 + lo], &h, &l);
        w1T_h[i] = h; w1T_l[i] = l;
    }
}

__global__ __launch_bounds__(256, 4)
void vnet_kernel(const float* __restrict__ state,
                 const float* __restrict__ t_w1, const float* __restrict__ t_b1,
                 const float* __restrict__ t_w2, const float* __restrict__ t_b2,
                 const float* __restrict__ w2,   const float* __restrict__ v_w1,
                 const float* __restrict__ v_b1, const float* __restrict__ v_w2,
                 const float* __restrict__ v_b2, const unsigned short* __restrict__ ws,
                 float* __restrict__ out)
{
    __shared__ __align__(16) unsigned short Xh[3 * XP], Xl[3 * XP];       // 9312 B each
    __shared__ __align__(16) unsigned short Eh[16 * ES];                  // 3328 B (E single)
    __shared__ __align__(16) unsigned short W0h[16 * WS], W1h[16 * WS];   // 1792 B each (single)
    __shared__ float a0c[112];     // A row 0 numerators (UNNORMALIZED); [97..111]=0
    __shared__ float e96b[2][16];  // double-buffered exp(S[n][96]) per strip
    __shared__ float invbS[16];    // per-strip 1/rowsum (wave 3, phase AB)
    __shared__ float a0w[16];      // a0c[s*16+n]*invbS[n] (wave 3, phase AB)
    __shared__ float pacc[64];     // p accumulator; [0..15] self-state temp at setup
    __shared__ float inv0s;        // 1/rowsum of strip0 row0 (head factor)

    const unsigned short* waT_h = ws;
    const unsigned short* waT_l = ws + 2304;
    const unsigned short* w1T_h = ws + 4608;
    const unsigned short* w1T_l = ws + 4608 + 3072;

    const int tid  = threadIdx.x;
    const int w    = tid >> 6;
    const int lane = tid & 63;
    const int row  = lane & 15;
    const int quad = lane >> 4;
    const int b    = blockIdx.x;
    const float* sb = state + (size_t)b * (96 * 64);
    const bf16x8 ZF = {0, 0, 0, 0, 0, 0, 0, 0};

    // ---------- stage X rows 1..96 into column panels ----------
    if (tid < 16) pacc[tid] = sb[tid];           // self-state temp
    for (int i = tid; i < 96 * 12; i += 256) {
        int r = i / 12, q = i % 12;
        float4 v = *(const float4*)(sb + r * 64 + 16 + 4 * q);
        unsigned short h0, l0, h1v, l1, h2, l2, h3, l3;
        split2(v.x, &h0, &l0); split2(v.y, &h1v, &l1);
        split2(v.z, &h2, &l2); split2(v.w, &h3, &l3);
        int m = 1 + r;
        int o = (q >> 2) * XP + m * 16 + (q & 3) * 4;
        *(uint2*)&Xh[o] = make_uint2((unsigned)h0 | ((unsigned)h1v << 16),
                                     (unsigned)h2 | ((unsigned)h3 << 16));
        *(uint2*)&Xl[o] = make_uint2((unsigned)l0 | ((unsigned)l1 << 16),
                                     (unsigned)l2 | ((unsigned)l3 << 16));
    }
    __syncthreads();

    // ---------- self MLP ----------
    if (tid < 50) {
        float a = t_b1[tid];
        #pragma unroll
        for (int i = 0; i < 16; ++i) a = fmaf(pacc[i], t_w1[i * 50 + tid], a);
        a0c[tid] = fmaxf(a, 0.f);                // hidden temp
    }
    __syncthreads();
    if (tid < 48) {                              // new_self -> X row0
        float a = t_b2[tid];
        for (int i = 0; i < 50; ++i) a = fmaf(a0c[i], t_w2[i * 48 + tid], a);
        unsigned short h, l; split2(fmaxf(a, 0.f), &h, &l);
        int o = (tid >> 4) * XP + (tid & 15);
        Xh[o] = h; Xl[o] = l;
    }
    if (tid >= 64 && tid < 128) pacc[tid - 64] = 0.f;     // p accumulator
    if (tid >= 128 && tid < 143) a0c[tid - 31] = 0.f;     // a0c[97..111] = 0
    __syncthreads();

    // ---------- step4 B-operand (X^T fragments) -> registers, ONCE ----------
    bf16x8 B4h[3], B4l[3];
    if (w < 3) {
        #pragma unroll
        for (int c3 = 0; c3 < 3; ++c3) {
            bf16x8 th, tl;
            #pragma unroll
            for (int j = 0; j < 8; ++j) {
                int e = w * XP + (32 * c3 + 8 * quad + j) * 16 + row;
                th[j] = (short)Xh[e];
                tl[j] = (short)Xl[e];
            }
            B4h[c3] = th;
            B4l[c3] = tl;
        }
    } else {
        #pragma unroll
        for (int c3 = 0; c3 < 3; ++c3) { B4h[c3] = ZF; B4l[c3] = ZF; }
    }

    // ---------- prologue: step1(0) -> W0 (single plane) ----------
    {
        if (w < 3) {
            f32x4 acc = {0.f, 0.f, 0.f, 0.f};
            #pragma unroll
            for (int ch = 0; ch < 2; ++ch) {
                int kb = 16 * ch;
                int c = kb + quad * 8;
                int o = (c >> 4) * XP + row * 16 + (c & 15);
                bf16x8 ah = ldf(&Xh[o]);
                bf16x8 al = ldf(&Xl[o]);
                if (ch == 1 && quad < 2) { ah = ZF; al = ZF; }
                bf16x8 bh = ldf(waT_h + (16 * w + row) * 48 + kb + quad * 8);
                bf16x8 bl = ldf(waT_l + (16 * w + row) * 48 + kb + quad * 8);
                acc = __builtin_amdgcn_mfma_f32_16x16x32_bf16(ah, bh, acc, 0, 0, 0);
                acc = __builtin_amdgcn_mfma_f32_16x16x32_bf16(ah, bl, acc, 0, 0, 0);
                acc = __builtin_amdgcn_mfma_f32_16x16x32_bf16(al, bh, acc, 0, 0, 0);
            }
            #pragma unroll
            for (int r = 0; r < 4; ++r)
                W0h[(quad * 4 + r) * WS + 16 * w + row] = rtne16(acc[r]);
        }
    }
    __syncthreads();
    // prologue: step2(0)+exp -> Eh; col-96 dot -> e96b[0], a0c[96]
    {
        bf16x8 a0h = ldf(&W0h[row * WS + quad * 8]);
        bf16x8 a1h = ldf(&W0h[row * WS + 16 + quad * 8]);
        if (quad < 2) a1h = ZF;
        for (int t = w; t < 6; t += 4) {
            int m = 16 * t + row;
            f32x4 acc = {0.f, 0.f, 0.f, 0.f};
            int o0 = (quad >> 1) * XP + m * 16 + (quad & 1) * 8;
            bf16x8 bh = ldf(&Xh[o0]);
            bf16x8 bl = ldf(&Xl[o0]);
            acc = __builtin_amdgcn_mfma_f32_16x16x32_bf16(a0h, bh, acc, 0, 0, 0);
            acc = __builtin_amdgcn_mfma_f32_16x16x32_bf16(a0h, bl, acc, 0, 0, 0);
            bh = ldf(&Xh[o0 + XP]);
            bl = ldf(&Xl[o0 + XP]);
            acc = __builtin_amdgcn_mfma_f32_16x16x32_bf16(a1h, bh, acc, 0, 0, 0);
            acc = __builtin_amdgcn_mfma_f32_16x16x32_bf16(a1h, bl, acc, 0, 0, 0);
            float e0v = __expf(acc[0]), e1v = __expf(acc[1]);
            float e2v = __expf(acc[2]), e3v = __expf(acc[3]);
            Eh[(quad * 4 + 0) * ES + m] = rtne16(e0v);
            Eh[(quad * 4 + 1) * ES + m] = rtne16(e1v);
            Eh[(quad * 4 + 2) * ES + m] = rtne16(e2v);
            Eh[(quad * 4 + 3) * ES + m] = rtne16(e3v);
            if (quad == 0) a0c[m] = e0v;          // row-0 numerators, fp32 unnorm
        }
        {   // col-96 dot for strip 0
            int rw = tid >> 4, mg = tid & 15;
            float s96 = 0.f;
            #pragma unroll
            for (int kk = 0; kk < 3; ++kk) {
                int c = mg + 16 * kk;
                float xw = bf2f(W0h[rw * WS + c]);
                float xv = bf2f(Xh[kk * XP + 1536 + mg]) + bf2f(Xl[kk * XP + 1536 + mg]);
                s96 = fmaf(xw, xv, s96);
            }
            s96 += __shfl_xor(s96, 1); s96 += __shfl_xor(s96, 2);
            s96 += __shfl_xor(s96, 4); s96 += __shfl_xor(s96, 8);
            if (mg == 0) {
                float e0 = __expf(s96);
                e96b[0][rw] = e0;
                if (rw == 0) a0c[96] = e0;
            }
        }
    }
    __syncthreads();

    // ---------- pipelined strip loop: 2 barriers/strip ----------
    for (int s = 0; s < 7; ++s) {
        unsigned short* Wsh = (s & 1) ? W1h : W0h;   // this strip (Xw dead -> AXu)
        unsigned short* Wnh = (s & 1) ? W0h : W1h;   // next strip's Xw
        const int sb_ = s & 1;

        // ---- phase AB: w<3: step4(s) unnorm + step1(s+1); w3: denom+a0w ----
        if (w < 3) {
            {   // step4(s): AXu = E@X + e96*X96 (NO invb), single-plane out
                f32x4 acc = {0.f, 0.f, 0.f, 0.f};
                #pragma unroll
                for (int c3 = 0; c3 < 3; ++c3) {
                    int mb = 32 * c3;
                    bf16x8 ah = ldf(&Eh[row * ES + mb + quad * 8]);
                    acc = __builtin_amdgcn_mfma_f32_16x16x32_bf16(ah, B4h[c3], acc, 0, 0, 0);
                    acc = __builtin_amdgcn_mfma_f32_16x16x32_bf16(ah, B4l[c3], acc, 0, 0, 0);
                }
                int j = 16 * w + row;
                float xv = bf2f(Xh[w * XP + 1536 + row]) + bf2f(Xl[w * XP + 1536 + row]);
                #pragma unroll
                for (int r = 0; r < 4; ++r) {
                    float v = fmaf(e96b[sb_][quad * 4 + r], xv, acc[r]);
                    Wsh[(quad * 4 + r) * WS + j] = rtne16(v);
                }
            }
            if (s < 6) {   // step1(s+1) -> Wn (single plane)
                f32x4 acc = {0.f, 0.f, 0.f, 0.f};
                int n = (s + 1) * 16 + row; int nc = n < 97 ? n : 96;  // strip-6 tail
                #pragma unroll
                for (int ch = 0; ch < 2; ++ch) {
                    int kb = 16 * ch;
                    int c = kb + quad * 8;
                    int o = (c >> 4) * XP + nc * 16 + (c & 15);
                    bf16x8 ah = ldf(&Xh[o]);
                    bf16x8 al = ldf(&Xl[o]);
                    if (ch == 1 && quad < 2) { ah = ZF; al = ZF; }
                    bf16x8 bh = ldf(waT_h + (16 * w + row) * 48 + kb + quad * 8);
                    bf16x8 bl = ldf(waT_l + (16 * w + row) * 48 + kb + quad * 8);
                    acc = __builtin_amdgcn_mfma_f32_16x16x32_bf16(ah, bh, acc, 0, 0, 0);
                    acc = __builtin_amdgcn_mfma_f32_16x16x32_bf16(ah, bl, acc, 0, 0, 0);
                    acc = __builtin_amdgcn_mfma_f32_16x16x32_bf16(al, bh, acc, 0, 0, 0);
                }
                #pragma unroll
                for (int r = 0; r < 4; ++r)
                    Wnh[(quad * 4 + r) * WS + 16 * w + row] = rtne16(acc[r]);
            }
        } else {
            // wave 3: denominators from ROUNDED Eh(s) + e96; then a0w
            int rw2  = lane >> 2;                 // 0..15 (row)
            int part = lane & 3;                  // 0..3  (24-elem chunk)
            const unsigned short* er = &Eh[rw2 * ES + part * 24];
            bf16x8 v0 = ldf(er), v1 = ldf(er + 8), v2 = ldf(er + 16);
            float ssum = 0.f;
            #pragma unroll
            for (int j = 0; j < 8; ++j)
                ssum += bf2f((unsigned short)v0[j]) + bf2f((unsigned short)v1[j])
                      + bf2f((unsigned short)v2[j]);
            ssum += __shfl_xor(ssum, 1);
            ssum += __shfl_xor(ssum, 2);
            if (part == 0) {
                float iv = 1.f / (ssum + e96b[sb_][rw2]);
                invbS[rw2] = iv;
                a0w[rw2] = a0c[s * 16 + rw2] * iv;
                if (s == 0 && rw2 == 0) inv0s = iv;
            }
        }
        __syncthreads();

        // ---- phase C: step5(s) [a0w post-relu] + step2(s+1)+exp + dot(w2,3) ----
        {   // h1 = invb*relu(AXu @ w1); p += a0w-weighted rows
            f32x4 acc = {0.f, 0.f, 0.f, 0.f};
            #pragma unroll
            for (int ch = 0; ch < 2; ++ch) {
                int kb = 16 * ch;
                bf16x8 ah = ldf(&Wsh[row * WS + kb + quad * 8]);
                if (ch == 1 && quad < 2) ah = ZF;
                bf16x8 bh = ldf(w1T_h + (16 * w + row) * 48 + kb + quad * 8);
                bf16x8 bl = ldf(w1T_l + (16 * w + row) * 48 + kb + quad * 8);
                acc = __builtin_amdgcn_mfma_f32_16x16x32_bf16(ah, bh, acc, 0, 0, 0);
                acc = __builtin_amdgcn_mfma_f32_16x16x32_bf16(ah, bl, acc, 0, 0, 0);
            }
            float part = 0.f;
            #pragma unroll
            for (int r = 0; r < 4; ++r)
                part += fmaxf(acc[r], 0.f) * a0w[quad * 4 + r];
            part += __shfl_xor(part, 16);
            part += __shfl_xor(part, 32);
            if (quad == 0) pacc[16 * w + row] += part;
        }
        if (s < 6) {   // step2(s+1)+exp -> Eh; dot by waves 2-3 -> e96b[(s+1)&1]
            bf16x8 a0h = ldf(&Wnh[row * WS + quad * 8]);
            bf16x8 a1h = ldf(&Wnh[row * WS + 16 + quad * 8]);
            if (quad < 2) a1h = ZF;
            for (int t = w; t < 6; t += 4) {
                int m = 16 * t + row;
                f32x4 acc = {0.f, 0.f, 0.f, 0.f};
                int o0 = (quad >> 1) * XP + m * 16 + (quad & 1) * 8;
                bf16x8 bh = ldf(&Xh[o0]);
                bf16x8 bl = ldf(&Xl[o0]);
                acc = __builtin_amdgcn_mfma_f32_16x16x32_bf16(a0h, bh, acc, 0, 0, 0);
                acc = __builtin_amdgcn_mfma_f32_16x16x32_bf16(a0h, bl, acc, 0, 0, 0);
                bh = ldf(&Xh[o0 + XP]);
                bl = ldf(&Xl[o0 + XP]);
                acc = __builtin_amdgcn_mfma_f32_16x16x32_bf16(a1h, bh, acc, 0, 0, 0);
                acc = __builtin_amdgcn_mfma_f32_16x16x32_bf16(a1h, bl, acc, 0, 0, 0);
                float e0v = __expf(acc[0]), e1v = __expf(acc[1]);
                float e2v = __expf(acc[2]), e3v = __expf(acc[3]);
                Eh[(quad * 4 + 0) * ES + m] = rtne16(e0v);
                Eh[(quad * 4 + 1) * ES + m] = rtne16(e1v);
                Eh[(quad * 4 + 2) * ES + m] = rtne16(e2v);
                Eh[(quad * 4 + 3) * ES + m] = rtne16(e3v);
            }
            if (tid >= 128) {   // col-96 dot for strip s+1 (waves 2-3)
                int rw2 = (tid >> 3) & 15;        // 16 rows, 8 lanes each
                int mg8 = tid & 7;
                float s96 = 0.f;
                #pragma unroll
                for (int kk = 0; kk < 6; ++kk) {
                    int c = mg8 + 8 * kk;
                    float xw = bf2f(Wnh[rw2 * WS + c]);
                    float xv = bf2f(Xh[(c >> 4) * XP + 1536 + (c & 15)])
                             + bf2f(Xl[(c >> 4) * XP + 1536 + (c & 15)]);
                    s96 = fmaf(xw, xv, s96);
                }
                s96 += __shfl_xor(s96, 1); s96 += __shfl_xor(s96, 2);
                s96 += __shfl_xor(s96, 4);
                if (mg8 == 0) e96b[(s + 1) & 1][rw2] = __expf(s96);
            }
        }
        __syncthreads();
    }

    // ---------- head (featb overlaid on a0c; a0c dead) ----------
    float* featb = a0c;
    if (tid < 64) {
        float a = 0.f;
        #pragma unroll 8
        for (int l = 0; l < 64; ++l) a = fmaf(pacc[l], w2[l * 64 + tid], a);
        featb[tid] = fmaxf(a * inv0s, 0.f);      // fold A-row-0 1/sum here
    }
    __syncthreads();
    if (tid < 64) {
        float a = v_b1[tid];
        #pragma unroll 8
        for (int c = 0; c < 64; ++c) a = fmaf(featb[c], v_w1[c * 64 + tid], a);
        float qd = fmaxf(a, 0.f) * v_w2[tid];
        #pragma unroll
        for (int d = 32; d >= 1; d >>= 1) qd += __shfl_xor(qd, d);
        if (tid == 0) out[b] = qd + v_b2[0];
    }
}

extern "C" void kernel_launch(void* const* d_in, const int* in_sizes, int n_in,
                              void* d_out, int out_size, void* d_ws, size_t ws_size,
                              hipStream_t stream) {
    (void)n_in; (void)ws_size; (void)out_size;
    const float* state = (const float*)d_in[0];
    const float* t_w1  = (const float*)d_in[1];
    const float* t_b1  = (const float*)d_in[2];
    const float* t_w2  = (const float*)d_in[3];
    const float* t_b2  = (const float*)d_in[4];
    const float* w_a   = (const float*)d_in[5];
    const float* w1    = (const float*)d_in[6];
    const float* w2    = (const float*)d_in[7];
    const float* v_w1  = (const float*)d_in[8];
    const float* v_b1  = (const float*)d_in[9];
    const float* v_w2  = (const float*)d_in[10];
    const float* v_b2  = (const float*)d_in[11];
    unsigned short* ws = (unsigned short*)d_ws;
    const int nb = in_sizes[0] / (96 * 64);   // 8192

    vnet_prep<<<1, 256, 0, stream>>>(w_a, w1, ws);
    vnet_kernel<<<nb, 256, 0, stream>>>(state, t_w1, t_b1, t_w2, t_b2, w2,
                                        v_w1, v_b1, v_w2, v_b2, ws, (float*)d_out);
}